// Round 1
// baseline (334.040 us; speedup 1.0000x reference)
//
#include <hip/hip_runtime.h>
#include <hip/hip_bf16.h>

// MultiCrossAttention: B=4, T=2048, C=768, H=12, HS=64
// Pipeline: cvt x/mem -> bf16 ; transpose weights -> [N][K] bf16 ;
//   GEMM q = x@Wq+bq ; GEMM kv = mem@Wkv+bkv ; flash attention ; GEMM out = y@Wproj+bproj
// All matmul via mfma_f32_16x16x32_bf16, fp32 accumulation.

#define B_  4
#define T_  2048
#define C_  768
#define H_  12
#define HS_ 64

typedef __attribute__((ext_vector_type(8))) short short8;   // 8 bf16 (4 VGPRs)
typedef __attribute__((ext_vector_type(4))) float f32x4;

__device__ __forceinline__ short f2bf(float f) {
    __hip_bfloat16 h = __float2bfloat16(f);
    return *reinterpret_cast<short*>(&h);
}

// ---------------- prepass kernels ----------------

__global__ void cvt_f32_to_bf16(const float* __restrict__ in, short* __restrict__ out, int n4) {
    int i = blockIdx.x * blockDim.x + threadIdx.x;
    if (i >= n4) return;
    float4 v = reinterpret_cast<const float4*>(in)[i];
    short4 o;
    o.x = f2bf(v.x); o.y = f2bf(v.y); o.z = f2bf(v.z); o.w = f2bf(v.w);
    reinterpret_cast<short4*>(out)[i] = o;
}

// out[n][k] = bf16(in[k][n]); in is [K][N] f32, out is [N][K] bf16
__global__ void wtrans_bf16(const float* __restrict__ in, short* __restrict__ out, int K, int N) {
    int idx = blockIdx.x * blockDim.x + threadIdx.x;
    if (idx >= K * N) return;
    int n = idx / K, k = idx - n * K;
    out[idx] = f2bf(in[(size_t)k * N + n]);
}

// ---------------- GEMM: C[M][N] = A[M][K] @ BT[N][K]^T + bias ----------------
// 128x128 block tile, 4 waves (2x2), each wave 64x64 (4x4 fragments of 16x16),
// BK=64 (2 mfma k-substeps). LDS padded [128][72] (144B stride -> ~2-way banks).

template<int OUT_F32>
__global__ void gemm_bf16_bt(const short* __restrict__ A, const short* __restrict__ BT,
                             const float* __restrict__ bias, void* __restrict__ out,
                             int M, int N, int K, int ldo) {
    __shared__ short As[128][72];
    __shared__ short Bs[128][72];
    const int m0 = blockIdx.y * 128;
    const int n0 = blockIdx.x * 128;
    const int t  = threadIdx.x;
    const int wid = t >> 6;
    const int wm = wid >> 1, wn = wid & 1;
    const int lane = t & 63;
    const int lr = lane & 15;
    const int lk = (lane >> 4) * 8;

    f32x4 acc[4][4] = {};

    const int sr = t >> 2;         // 0..63
    const int sc = (t & 3) * 16;   // 0,16,32,48 (shorts)

    for (int k0 = 0; k0 < K; k0 += 64) {
        __syncthreads();
        #pragma unroll
        for (int rr = 0; rr < 128; rr += 64) {
            int r = sr + rr;
            const short* ga = &A [(size_t)(m0 + r) * K + k0 + sc];
            const short* gb = &BT[(size_t)(n0 + r) * K + k0 + sc];
            uint4 a0 = *reinterpret_cast<const uint4*>(ga);
            uint4 a1 = *reinterpret_cast<const uint4*>(ga + 8);
            uint4 b0 = *reinterpret_cast<const uint4*>(gb);
            uint4 b1 = *reinterpret_cast<const uint4*>(gb + 8);
            *reinterpret_cast<uint4*>(&As[r][sc])     = a0;
            *reinterpret_cast<uint4*>(&As[r][sc + 8]) = a1;
            *reinterpret_cast<uint4*>(&Bs[r][sc])     = b0;
            *reinterpret_cast<uint4*>(&Bs[r][sc + 8]) = b1;
        }
        __syncthreads();

        #pragma unroll
        for (int ks = 0; ks < 2; ++ks) {
            const int kk = ks * 32 + lk;
            short8 a[4], b[4];
            #pragma unroll
            for (int m = 0; m < 4; ++m)
                a[m] = *reinterpret_cast<const short8*>(&As[wm*64 + m*16 + lr][kk]);
            #pragma unroll
            for (int n = 0; n < 4; ++n)
                b[n] = *reinterpret_cast<const short8*>(&Bs[wn*64 + n*16 + lr][kk]);
            #pragma unroll
            for (int m = 0; m < 4; ++m)
                #pragma unroll
                for (int n = 0; n < 4; ++n)
                    acc[m][n] = __builtin_amdgcn_mfma_f32_16x16x32_bf16(a[m], b[n], acc[m][n], 0, 0, 0);
        }
    }

    // epilogue: D layout col = lane&15, row = (lane>>4)*4 + j   [m89-verified]
    const int rb = m0 + wm * 64;
    const int cb = n0 + wn * 64;
    const int rj = (lane >> 4) * 4;
    #pragma unroll
    for (int n = 0; n < 4; ++n) {
        const int col = cb + n * 16 + lr;
        const float bv = bias[col];
        #pragma unroll
        for (int m = 0; m < 4; ++m) {
            #pragma unroll
            for (int j = 0; j < 4; ++j) {
                const int row = rb + m * 16 + rj + j;
                const float v = acc[m][n][j] + bv;
                if (OUT_F32)
                    reinterpret_cast<float*>(out)[(size_t)row * ldo + col] = v;
                else
                    reinterpret_cast<short*>(out)[(size_t)row * ldo + col] = f2bf(v);
            }
        }
    }
}

// ---------------- flash attention ----------------
// grid (T/64, H, B), block 256 (4 waves). Wave w owns q-rows [q0+w*16, q0+w*16+16).
// KV chunk = 64. Online softmax with per-row (m,l) state, wave-parallel reduce
// over the 16 lanes that share a row (shfl_xor masks 1,2,4,8).

__global__ void attn_fwd(const short* __restrict__ qb, const short* __restrict__ kvb,
                         short* __restrict__ yb) {
    __shared__ short Ks[64][72];      // K chunk  [kv][d]
    __shared__ short Vt[64][72];      // V chunk transposed [d][kv]
    __shared__ short Pl[4][16][72];   // per-wave P tile [row][kv]

    const int b = blockIdx.z, h = blockIdx.y;
    const int q0 = blockIdx.x * 64;
    const int t = threadIdx.x;
    const int w = t >> 6;
    const int lane = t & 63;
    const int lr = lane & 15;
    const int g = lane >> 4;
    const int lk = g * 8;

    // Q fragments held in registers for the whole KV loop
    const size_t qoff = (size_t)(b * T_ + q0 + w * 16 + lr) * C_ + h * HS_;
    short8 aq[2];
    aq[0] = *reinterpret_cast<const short8*>(&qb[qoff + lk]);
    aq[1] = *reinterpret_cast<const short8*>(&qb[qoff + 32 + lk]);

    f32x4 acc_y[4] = {};
    float m_run[4], l_run[4];
    #pragma unroll
    for (int j = 0; j < 4; ++j) { m_run[j] = -1e30f; l_run[j] = 0.f; }

    for (int kv0 = 0; kv0 < T_; kv0 += 64) {
        __syncthreads();
        // stage K chunk (vectorized) and V chunk transposed (scalar)
        #pragma unroll
        for (int ch = t; ch < 512; ch += 256) {
            int r = ch >> 3, c = (ch & 7) * 8;
            *reinterpret_cast<uint4*>(&Ks[r][c]) =
                *reinterpret_cast<const uint4*>(&kvb[(size_t)(b*T_ + kv0 + r) * (2*C_) + h*HS_ + c]);
        }
        #pragma unroll
        for (int i = 0; i < 16; ++i) {
            int idx = t + i * 256;
            int kv = idx >> 6, d = idx & 63;
            Vt[d][kv] = kvb[(size_t)(b*T_ + kv0 + kv) * (2*C_) + C_ + h*HS_ + d];
        }
        __syncthreads();

        // S = (Q K^T) * scale
        f32x4 s[4] = {};
        #pragma unroll
        for (int ks = 0; ks < 2; ++ks) {
            const int kk = ks * 32 + lk;
            #pragma unroll
            for (int n = 0; n < 4; ++n) {
                short8 bk = *reinterpret_cast<const short8*>(&Ks[n*16 + lr][kk]);
                s[n] = __builtin_amdgcn_mfma_f32_16x16x32_bf16(aq[ks], bk, s[n], 0, 0, 0);
            }
        }
        #pragma unroll
        for (int n = 0; n < 4; ++n) s[n] *= 0.125f;   // 1/sqrt(64)

        // online softmax; lane holds rows (g*4+j), cols (n*16+lr)
        float pr[4][4];
        #pragma unroll
        for (int j = 0; j < 4; ++j) {
            float mx = -1e30f;
            #pragma unroll
            for (int n = 0; n < 4; ++n) mx = fmaxf(mx, s[n][j]);
            #pragma unroll
            for (int off = 8; off >= 1; off >>= 1)
                mx = fmaxf(mx, __shfl_xor(mx, off, 64));
            const float mnew = fmaxf(m_run[j], mx);
            const float corr = __expf(m_run[j] - mnew);
            float psum = 0.f;
            #pragma unroll
            for (int n = 0; n < 4; ++n) {
                float p = __expf(s[n][j] - mnew);
                pr[n][j] = p;
                psum += p;
            }
            #pragma unroll
            for (int off = 8; off >= 1; off >>= 1)
                psum += __shfl_xor(psum, off, 64);
            l_run[j] = l_run[j] * corr + psum;
            m_run[j] = mnew;
            #pragma unroll
            for (int n = 0; n < 4; ++n) acc_y[n][j] *= corr;
        }

        // P -> LDS (bf16), wave-private tile; same-wave in-order LDS makes this safe
        #pragma unroll
        for (int n = 0; n < 4; ++n)
            #pragma unroll
            for (int j = 0; j < 4; ++j)
                Pl[w][g*4 + j][n*16 + lr] = f2bf(pr[n][j]);

        // Y += P @ V
        #pragma unroll
        for (int ks = 0; ks < 2; ++ks) {
            const int kk = ks * 32 + lk;
            short8 ap = *reinterpret_cast<const short8*>(&Pl[w][lr][kk]);
            #pragma unroll
            for (int n = 0; n < 4; ++n) {
                short8 bv = *reinterpret_cast<const short8*>(&Vt[n*16 + lr][kk]);
                acc_y[n] = __builtin_amdgcn_mfma_f32_16x16x32_bf16(ap, bv, acc_y[n], 0, 0, 0);
            }
        }
    }

    // epilogue: y[row][d] = acc / l  ; write bf16 into yb ([B*T][C] layout)
    const size_t yrow0 = (size_t)(b * T_ + q0 + w * 16);
    #pragma unroll
    for (int j = 0; j < 4; ++j) {
        const float inv = 1.f / l_run[j];
        const int row = g * 4 + j;
        #pragma unroll
        for (int n = 0; n < 4; ++n)
            yb[(yrow0 + row) * C_ + h*HS_ + n*16 + lr] = f2bf(acc_y[n][j] * inv);
    }
}

// ---------------- launch ----------------

extern "C" void kernel_launch(void* const* d_in, const int* in_sizes, int n_in,
                              void* d_out, int out_size, void* d_ws, size_t ws_size,
                              hipStream_t stream) {
    const float* x      = (const float*)d_in[0];
    const float* memory = (const float*)d_in[1];
    const float* Wq     = (const float*)d_in[2];
    const float* bq     = (const float*)d_in[3];
    const float* Wkv    = (const float*)d_in[4];
    const float* bkv    = (const float*)d_in[5];
    const float* Wproj  = (const float*)d_in[6];
    const float* bproj  = (const float*)d_in[7];

    char* ws = (char*)d_ws;
    size_t off = 0;
    auto alloc = [&](size_t bytes) { char* p = ws + off; off += (bytes + 255) & ~(size_t)255; return p; };
    short* xb   = (short*)alloc((size_t)8192 * 768 * 2);   // x bf16, reused as y after attention
    short* memb = (short*)alloc((size_t)8192 * 768 * 2);
    short* qb   = (short*)alloc((size_t)8192 * 768 * 2);
    short* kvb  = (short*)alloc((size_t)8192 * 1536 * 2);
    short* WqT  = (short*)alloc((size_t)768 * 768 * 2);
    short* WkvT = (short*)alloc((size_t)1536 * 768 * 2);
    short* WpT  = (short*)alloc((size_t)768 * 768 * 2);

    const int n = 8192 * 768;
    cvt_f32_to_bf16<<<n/4/256, 256, 0, stream>>>(x, xb, n/4);
    cvt_f32_to_bf16<<<n/4/256, 256, 0, stream>>>(memory, memb, n/4);
    wtrans_bf16<<<(768*768  + 255)/256, 256, 0, stream>>>(Wq,    WqT,  768, 768);
    wtrans_bf16<<<(768*1536 + 255)/256, 256, 0, stream>>>(Wkv,   WkvT, 768, 1536);
    wtrans_bf16<<<(768*768  + 255)/256, 256, 0, stream>>>(Wproj, WpT,  768, 768);

    gemm_bf16_bt<0><<<dim3( 6, 64), 256, 0, stream>>>(xb,   WqT,  bq,   qb,  8192,  768, 768,  768);
    gemm_bf16_bt<0><<<dim3(12, 64), 256, 0, stream>>>(memb, WkvT, bkv,  kvb, 8192, 1536, 768, 1536);
    attn_fwd<<<dim3(T_/64, H_, B_), 256, 0, stream>>>(qb, kvb, xb /* y reuses xb */);
    gemm_bf16_bt<1><<<dim3( 6, 64), 256, 0, stream>>>(xb,   WpT,  bproj, d_out, 8192, 768, 768, 768);
}